// Round 3
// baseline (13485.876 us; speedup 1.0000x reference)
//
#include <hip/hip_runtime.h>
#include <stdint.h>
#include <math.h>

// ---------------------------------------------------------------------------
// ODE-LSTM on MI355X -- persistent round. Inputs f32, outputs f32.
// B=4096, OBS=256, H=1024, OUT=256, T=20 (19 RK4 steps).
//
//   1. transpose+cast weights f32 -> bf16 N x K (ws)
//   2. init: hs(f32, d_out overlay) = h, z(bf16, ws) = h, cnt[64] = 0
//   3. rk4_loop (ONE persistent dispatch, 1024 blocks = exact residency):
//      152 GEMM phases; phase p even: t1 = tanh(z@W1+b1); odd: k = t1@W2+b2
//      + RK4 update. Inter-phase sync is per-64-row-panel (cnt[by] reaches
//      16*p before anyone starts phase p -- proven gate invariant), with
//      agent-scope release/acquire fences for cross-XCD safety.
//   4. fused dual GEMM: gate=sigm([x|h]@Wi+bi), ct=sigm([x|z]@Wi+bi),
//      c_new = gate*(c+ct), h_new = gate*tanh(c_new)  -> d_out (f32)
//   5. out = h_new @ Wo + bo                  (MODE 4) -> d_out (f32)
//
// R10: R9 hit 18 us/GEMM (152 dispatches); floors: MFMA 3.6, L2 7.4, LDS ~10.
// The residual was per-dispatch full-grid drain + launch gaps (~4 us each).
// This round folds all 152 GEMMs into one persistent kernel with row-panel
// semaphores (dependency is panel-local: phase p block (bx,by) needs only
// the 16 blocks (*,by) of phase p-1). K-accumulation order unchanged.
//
// ws (15 MB): W1T[0,2M) W2T[2,4M) WiT[4,6.5M) WoT[6.5,7M) z[7,15M)
// d_out (37.75 MB f32) overlays during loop (all dead before final writes):
//   hs f32 @ bytes [0,16M) | ksum bf16 @ [16,24M) | t1 bf16 @ [24,32M)
//   cnt u32 @ [32M,32M+256) (inside c_new's final span, rewritten later)
// final: out f32 @ elems [0,1M) | h_new @ [1M,5.25M) | c_new @ [5.25M,9.44M)
// ---------------------------------------------------------------------------

typedef __attribute__((ext_vector_type(8))) short short8;
typedef __attribute__((ext_vector_type(4))) float float4v;

#define BM 128  // gemm_fused only
#define BN 128
#define BK 64

__device__ __forceinline__ float bf2f(unsigned short u) {
  union { unsigned int i; float f; } x;
  x.i = ((unsigned int)u) << 16;
  return x.f;
}
__device__ __forceinline__ unsigned short f2bf(float f) {
  union { float f; unsigned int i; } x;
  x.f = f;
  unsigned int r = x.i + 0x7fffu + ((x.i >> 16) & 1u);  // RNE
  return (unsigned short)(r >> 16);
}
__device__ __forceinline__ void load16(const void* g, void* l) {
  __builtin_amdgcn_global_load_lds(
      (__attribute__((address_space(1))) void*)g,
      (__attribute__((address_space(3))) void*)l, 16, 0, 0);
}
__device__ __forceinline__ short8 packbf8(const float* p) {
  float4v lo = *(const float4v*)p, hi = *(const float4v*)(p + 4);
  short8 s;
  s[0] = (short)f2bf(lo[0]); s[1] = (short)f2bf(lo[1]);
  s[2] = (short)f2bf(lo[2]); s[3] = (short)f2bf(lo[3]);
  s[4] = (short)f2bf(hi[0]); s[5] = (short)f2bf(hi[1]);
  s[6] = (short)f2bf(hi[2]); s[7] = (short)f2bf(hi[3]);
  return s;
}

// ---------------------------------------------------------------------------
// Persistent RK4 loop: 152 GEMM phases, panel-semaphore pipelined.
// 1024 blocks (= exact resident capacity at 4 blocks/CU), 64x64 tiles.
// Block mapping (static): lin -> XCD stripe: xcd = lin&7 owns by = xcd*8..+7,
// all 16 bx. Producer and consumer of a panel share an XCD (perf); fences
// are agent-scope so correctness holds for ANY block->XCD mapping.
// ---------------------------------------------------------------------------
__global__ __launch_bounds__(256, 4) void rk4_loop(
    const unsigned short* __restrict__ W1T,
    const unsigned short* __restrict__ W2T,
    const float* __restrict__ b1, const float* __restrict__ b2,
    const float* __restrict__ tgrid,
    float* __restrict__ hsF,
    unsigned short* __restrict__ ksumB,
    unsigned short* __restrict__ zB,
    unsigned short* __restrict__ t1B,
    unsigned int* __restrict__ cnt) {
  __shared__ short8 AsV[2][512];  // 64 rows x 8 swizzled chunks, dbuf = 16 KB
  __shared__ short8 BsV[2][512];

  const int t = threadIdx.x;
  const int lin = blockIdx.x;
  const int xcd = lin & 7, j = lin >> 3;
  const int bx = j & 15;
  const int by = (xcd << 3) | (j >> 4);
  const int mBase = by * 64, nBase = bx * 64;
  const int wave = t >> 6, lane = t & 63;
  const int wr = wave >> 1, wc = wave & 1;
  const int q = lane >> 4, m16 = lane & 15;
  const int r0 = t >> 3;               // staging row 0..31 (also row+32)
  const int kcl = (t & 7) ^ (r0 & 7);  // swizzled k-chunk ((r0+32)&7 == r0&7)

  const size_t aOff = (size_t)(mBase + r0) * 1024 + kcl * 8;
  const size_t bOff = (size_t)(nBase + r0) * 1024 + kcl * 8;
  const unsigned short* const aP[2] = {zB + aOff, t1B + aOff};
  const unsigned short* const bP[2] = {W1T + bOff, W2T + bOff};
  const float* const biasP[2] = {b1, b2};

  const int colBase = nBase + wc * 32 + m16;
  const int rowBase = mBase + wr * 32 + q * 4;

#pragma unroll 1
  for (int p = 0; p < 152; ++p) {
    const int g = p & 1;
    if (p > 0) {
      // Gate: nobody starts phase p until cnt[by] == 16*p, i.e. all 16
      // panel blocks finished phase p-1 (invariant: counter can only reach
      // 16*p when every block's completed-count is exactly p).
      if (t == 0) {
        const unsigned int tgt = 16u * (unsigned int)p;
        while (__hip_atomic_load(cnt + by, __ATOMIC_RELAXED,
                                 __HIP_MEMORY_SCOPE_AGENT) < tgt)
          __builtin_amdgcn_s_sleep(2);
        __builtin_amdgcn_fence(__ATOMIC_ACQUIRE, "agent");  // inv L1(+L2)
      }
      __syncthreads();  // also fences laggard computeT vs upcoming stageT
    }

    const unsigned short* aU = aP[g];
    const unsigned short* bG = bP[g];
    const int step = p >> 3;
    const float dtv = tgrid[step + 1] - tgrid[step];

    float4v acc[2][2];
#pragma unroll
    for (int r = 0; r < 2; ++r)
#pragma unroll
      for (int c = 0; c < 2; ++c) acc[r][c] = (float4v){0.f, 0.f, 0.f, 0.f};

    auto stageT = [&](int buf, int k0) {
      load16(aU + k0, &AsV[buf][t]);
      load16(aU + 32 * 1024 + k0, &AsV[buf][t + 256]);
      load16(bG + k0, &BsV[buf][t]);
      load16(bG + 32 * 1024 + k0, &BsV[buf][t + 256]);
    };
    auto computeT = [&](int buf) {
#pragma unroll
      for (int kk = 0; kk < 2; ++kk) {
        const int kc = kk * 4 + q;
        short8 af[2], bfr[2];
#pragma unroll
        for (int r = 0; r < 2; ++r) {
          const int arow = wr * 32 + r * 16 + m16;
          af[r] = AsV[buf][arow * 8 + (kc ^ (arow & 7))];
          const int brow = wc * 32 + r * 16 + m16;
          bfr[r] = BsV[buf][brow * 8 + (kc ^ (brow & 7))];
        }
#pragma unroll
        for (int r = 0; r < 2; ++r)
#pragma unroll
          for (int c = 0; c < 2; ++c)
            acc[r][c] = __builtin_amdgcn_mfma_f32_16x16x32_bf16(
                af[r], bfr[c], acc[r][c], 0, 0, 0);
      }
    };

    // ---- 2-phase double-buffered K-loop, counted vmcnt(4) ----
    stageT(0, 0);
    int cur = 0;
#pragma unroll 1
    for (int k0 = BK; k0 < 1024; k0 += BK) {
      stageT(cur ^ 1, k0);  // next tile's 4 loads join the queue
      asm volatile("s_waitcnt vmcnt(4)" ::: "memory");
      __builtin_amdgcn_sched_barrier(0);
      __builtin_amdgcn_s_barrier();
      __builtin_amdgcn_sched_barrier(0);
      computeT(cur);
      asm volatile("s_waitcnt lgkmcnt(0)" ::: "memory");
      __builtin_amdgcn_sched_barrier(0);
      __builtin_amdgcn_s_barrier();
      __builtin_amdgcn_sched_barrier(0);
      cur ^= 1;
    }
    asm volatile("s_waitcnt vmcnt(0)" ::: "memory");
    __builtin_amdgcn_sched_barrier(0);
    __builtin_amdgcn_s_barrier();
    __builtin_amdgcn_sched_barrier(0);
    computeT(cur);

    // ---- epilogue ----
    const float* bias = biasP[g];
    const int stg = ((p >> 1) & 3) + 1;
#pragma unroll
    for (int r = 0; r < 2; ++r) {
#pragma unroll
      for (int c = 0; c < 2; ++c) {
        const int col = colBase + c * 16;
        const float bv = bias[col];
#pragma unroll
        for (int e = 0; e < 4; ++e) {
          const int row = rowBase + r * 16 + e;
          const size_t idx = (size_t)row * 1024 + col;
          const float v = acc[r][c][e] + bv;
          if (g == 0) {  // t1 = tanh(.)
            t1B[idx] = f2bf(tanhf(v));
          } else {  // RK4 stage update (ksum/hs are block-private across p)
            const float hv = hsF[idx];
            float zn;
            if (stg == 1) {
              ksumB[idx] = f2bf(v);
              zn = hv + 0.5f * dtv * v;
            } else if (stg == 2) {
              ksumB[idx] = f2bf(bf2f(ksumB[idx]) + 2.f * v);
              zn = hv + 0.5f * dtv * v;
            } else if (stg == 3) {
              ksumB[idx] = f2bf(bf2f(ksumB[idx]) + 2.f * v);
              zn = hv + dtv * v;
            } else {
              zn = hv + (dtv * (1.f / 6.f)) * (bf2f(ksumB[idx]) + v);
              hsF[idx] = zn;
            }
            zB[idx] = f2bf(zn);
          }
        }
      }
    }

    __syncthreads();  // drains every wave's stores (vmcnt0) to local L2
    if (t == 0) {
      __builtin_amdgcn_fence(__ATOMIC_RELEASE, "agent");  // wbl2 -> visible
      __hip_atomic_fetch_add(cnt + by, 1u, __ATOMIC_RELAXED,
                             __HIP_MEMORY_SCOPE_AGENT);
    }
  }
}

// C = A(MxK row-major) * Bt(NxK bf16 row-major)^T + bias, fused epilogue.
// 64x64 tiles; only MODE4/ADT0 (final out-projection) is instantiated now.
template <int MODE, int ADT>
__global__ __launch_bounds__(256, 4) void gemm_bt(
    const void* __restrict__ Av, const unsigned short* __restrict__ Bt,
    int N, int K, const float* __restrict__ bias,
    const float* __restrict__ tgrid, int step, int stage,
    float* __restrict__ hsF,
    unsigned short* __restrict__ ksumB,
    unsigned short* __restrict__ zB,
    unsigned short* __restrict__ t1B,
    float* __restrict__ outF) {
  __shared__ short8 AsV[2][512];
  __shared__ short8 BsV[2][512];

  const int t = threadIdx.x;
  int bx = blockIdx.x, by = blockIdx.y;
  if (gridDim.x == 16 && gridDim.y == 64) {
    const int lin = bx + (by << 4);
    const int x = lin & 7, j = lin >> 3;
    bx = j & 15;
    by = (x << 3) | (j >> 4);
  }
  const int mBase = by * 64, nBase = bx * 64;
  const int wave = t >> 6, lane = t & 63;
  const int wr = wave >> 1, wc = wave & 1;
  const int q = lane >> 4, m16 = lane & 15;

  float4v acc[2][2];
#pragma unroll
  for (int r = 0; r < 2; ++r)
#pragma unroll
    for (int c = 0; c < 2; ++c) acc[r][c] = (float4v){0.f, 0.f, 0.f, 0.f};

  const int r0 = t >> 3;
  const int kcl = (t & 7) ^ (r0 & 7);
  const unsigned short* aU = (const unsigned short*)Av + (size_t)(mBase + r0) * K + kcl * 8;
  const float* aF = (const float*)Av + (size_t)(mBase + r0) * K + kcl * 8;
  const unsigned short* bG = Bt + (size_t)(nBase + r0) * K + kcl * 8;

  auto computeT = [&](int buf) {
#pragma unroll
    for (int kk = 0; kk < 2; ++kk) {
      const int kc = kk * 4 + q;
      short8 af[2], bfr[2];
#pragma unroll
      for (int r = 0; r < 2; ++r) {
        const int arow = wr * 32 + r * 16 + m16;
        af[r] = AsV[buf][arow * 8 + (kc ^ (arow & 7))];
        const int brow = wc * 32 + r * 16 + m16;
        bfr[r] = BsV[buf][brow * 8 + (kc ^ (brow & 7))];
      }
#pragma unroll
      for (int r = 0; r < 2; ++r)
#pragma unroll
        for (int c = 0; c < 2; ++c)
          acc[r][c] = __builtin_amdgcn_mfma_f32_16x16x32_bf16(af[r], bfr[c],
                                                              acc[r][c], 0, 0, 0);
    }
  };

  if constexpr (ADT == 1) {
    auto stageT = [&](int buf, int k0) {
      load16(aU + k0, &AsV[buf][t]);
      load16(aU + (size_t)32 * K + k0, &AsV[buf][t + 256]);
      load16(bG + k0, &BsV[buf][t]);
      load16(bG + (size_t)32 * K + k0, &BsV[buf][t + 256]);
    };
    stageT(0, 0);
    int cur = 0;
    for (int k0 = BK; k0 < K; k0 += BK) {
      stageT(cur ^ 1, k0);
      asm volatile("s_waitcnt vmcnt(4)" ::: "memory");
      __builtin_amdgcn_sched_barrier(0);
      __builtin_amdgcn_s_barrier();
      __builtin_amdgcn_sched_barrier(0);
      computeT(cur);
      asm volatile("s_waitcnt lgkmcnt(0)" ::: "memory");
      __builtin_amdgcn_sched_barrier(0);
      __builtin_amdgcn_s_barrier();
      __builtin_amdgcn_sched_barrier(0);
      cur ^= 1;
    }
    asm volatile("s_waitcnt vmcnt(0)" ::: "memory");
    __builtin_amdgcn_sched_barrier(0);
    __builtin_amdgcn_s_barrier();
    __builtin_amdgcn_sched_barrier(0);
    computeT(cur);
  } else {
    for (int k0 = 0; k0 < K; k0 += BK) {
      AsV[0][t] = packbf8(aF + k0);
      AsV[0][t + 256] = packbf8(aF + (size_t)32 * K + k0);
      load16(bG + k0, &BsV[0][t]);
      load16(bG + (size_t)32 * K + k0, &BsV[0][t + 256]);
      __builtin_amdgcn_s_waitcnt(0);
      __syncthreads();
      computeT(0);
      __syncthreads();
    }
  }

  const float dtv = (MODE == 1) ? (tgrid[step + 1] - tgrid[step]) : 0.f;
  const int colBase = nBase + wc * 32 + m16;
  const int rowBase = mBase + wr * 32 + q * 4;
#pragma unroll
  for (int r = 0; r < 2; ++r) {
#pragma unroll
    for (int c = 0; c < 2; ++c) {
      const int col = colBase + c * 16;
      const float bv = bias[col];
#pragma unroll
      for (int e = 0; e < 4; ++e) {
        const int row = rowBase + r * 16 + e;
        const size_t idx = (size_t)row * N + col;
        const float v = acc[r][c][e] + bv;
        if (MODE == 0) {
          t1B[idx] = f2bf(tanhf(v));
        } else if (MODE == 1) {
          const float hv = hsF[idx];
          float zn;
          if (stage == 1) {
            ksumB[idx] = f2bf(v);
            zn = hv + 0.5f * dtv * v;
          } else if (stage == 2) {
            ksumB[idx] = f2bf(bf2f(ksumB[idx]) + 2.f * v);
            zn = hv + 0.5f * dtv * v;
          } else if (stage == 3) {
            ksumB[idx] = f2bf(bf2f(ksumB[idx]) + 2.f * v);
            zn = hv + dtv * v;
          } else {
            zn = hv + (dtv * (1.f / 6.f)) * (bf2f(ksumB[idx]) + v);
            hsF[idx] = zn;
          }
          zB[idx] = f2bf(zn);
        } else {
          outF[idx] = v;
        }
      }
    }
  }
}

// Fused gate + c_tilde dual GEMM: accG = [x|h] @ WiT^T, accC = [x|z] @ WiT^T;
// epilogue computes c_new / h_new directly. grid (8, 32), 128x128 tiles.
__global__ __launch_bounds__(256, 1) void gemm_fused(
    const float* __restrict__ x, const float* __restrict__ h,
    const unsigned short* __restrict__ zB,
    const unsigned short* __restrict__ WiT,  // 1024 x 1280 bf16
    const float* __restrict__ bi, const float* __restrict__ c_in,
    float* __restrict__ hnewF, float* __restrict__ cnewF) {
  __shared__ short8 AsG[1024];
  __shared__ short8 AsC[1024];
  __shared__ short8 BsV[1024];

  const int t = threadIdx.x;
  int bx = blockIdx.x, by = blockIdx.y;
  if (gridDim.x == 8 && gridDim.y == 32) {
    const int lin = bx + (by << 3);
    const int x = lin & 7;
    const int j = lin >> 3;
    bx = ((x & 1) << 2) | (j & 3);
    by = ((x >> 1) << 3) | (j >> 2);
  }
  const int mBase = by * BM, nBase = bx * BN;
  const int wave = t >> 6, lane = t & 63;
  const int wr = wave >> 1, wc = wave & 1;
  const int q = lane >> 4, m16 = lane & 15;

  float4v accG[4][4], accC[4][4];
#pragma unroll
  for (int r = 0; r < 4; ++r)
#pragma unroll
    for (int c = 0; c < 4; ++c) {
      accG[r][c] = (float4v){0.f, 0.f, 0.f, 0.f};
      accC[r][c] = (float4v){0.f, 0.f, 0.f, 0.f};
    }

  const int r0 = t >> 3;
  const int kcl = (t & 7) ^ (r0 & 7);

  for (int k0 = 0; k0 < 1280; k0 += BK) {
    const bool isX = (k0 < 256);
#pragma unroll
    for (int i = 0; i < 4; ++i) {
      const int row = mBase + r0 + i * 32;
      const float* gp = isX ? (x + (size_t)row * 256 + k0 + kcl * 8)
                            : (h + (size_t)row * 1024 + (k0 - 256) + kcl * 8);
      const short8 sg = packbf8(gp);
      AsG[i * 256 + t] = sg;
      if (isX)
        AsC[i * 256 + t] = sg;
      else
        AsC[i * 256 + t] = *(const short8*)(zB + (size_t)row * 1024 + (k0 - 256) + kcl * 8);
      load16(WiT + (size_t)(nBase + r0 + i * 32) * 1280 + k0 + kcl * 8,
             &BsV[i * 256 + t]);
    }
    __builtin_amdgcn_s_waitcnt(0);
    __syncthreads();

#pragma unroll
    for (int kk = 0; kk < 2; ++kk) {
      const int kc = kk * 4 + q;
      short8 ag[4], ac[4], bfr[4];
#pragma unroll
      for (int r = 0; r < 4; ++r) {
        const int arow = wr * 64 + r * 16 + m16;
        ag[r] = AsG[arow * 8 + (kc ^ (arow & 7))];
        ac[r] = AsC[arow * 8 + (kc ^ (arow & 7))];
        const int brow = wc * 64 + r * 16 + m16;
        bfr[r] = BsV[brow * 8 + (kc ^ (brow & 7))];
      }
#pragma unroll
      for (int r = 0; r < 4; ++r)
#pragma unroll
        for (int c = 0; c < 4; ++c) {
          accG[r][c] = __builtin_amdgcn_mfma_f32_16x16x32_bf16(ag[r], bfr[c],
                                                               accG[r][c], 0, 0, 0);
          accC[r][c] = __builtin_amdgcn_mfma_f32_16x16x32_bf16(ac[r], bfr[c],
                                                               accC[r][c], 0, 0, 0);
        }
    }
    __syncthreads();
  }

  const int colBase = nBase + wc * 64 + m16;
  const int rowBase = mBase + wr * 64 + q * 4;
#pragma unroll
  for (int r = 0; r < 4; ++r) {
#pragma unroll
    for (int c = 0; c < 4; ++c) {
      const int col = colBase + c * 16;
      const float bv = bi[col];
#pragma unroll
      for (int e = 0; e < 4; ++e) {
        const int row = rowBase + r * 16 + e;
        const size_t idx = (size_t)row * 1024 + col;
        const float g = 1.f / (1.f + expf(-(accG[r][c][e] + bv)));
        const float ct = 1.f / (1.f + expf(-(accC[r][c][e] + bv)));
        const float cn = g * (c_in[idx] + ct);
        const float hn = g * tanhf(cn);
        hnewF[idx] = hn;
        cnewF[idx] = cn;
      }
    }
  }
}

// out[c][r] = bf16(in[r][c]); in f32 RxC. block (32,8), grid (C/32, R/32).
__global__ __launch_bounds__(256) void transpose_f32_bf16(
    const float* __restrict__ in, unsigned short* __restrict__ out,
    int R, int C) {
  __shared__ float tile[32][33];
  const int c0 = blockIdx.x * 32, r0 = blockIdx.y * 32;
  const int tx = threadIdx.x, ty = threadIdx.y;
#pragma unroll
  for (int i = 0; i < 32; i += 8)
    tile[ty + i][tx] = in[(size_t)(r0 + ty + i) * C + c0 + tx];
  __syncthreads();
#pragma unroll
  for (int i = 0; i < 32; i += 8)
    out[(size_t)(c0 + ty + i) * R + r0 + tx] = f2bf(tile[tx][ty + i]);
}

__global__ __launch_bounds__(256) void init_h_kernel(
    const float* __restrict__ h, float* __restrict__ hsF,
    unsigned short* __restrict__ zB, unsigned int* __restrict__ cnt) {
  const int i = blockIdx.x * 256 + threadIdx.x;
  const float hv = h[i];
  hsF[i] = hv;
  zB[i] = f2bf(hv);
  if (blockIdx.x == 0 && threadIdx.x < 64) cnt[threadIdx.x] = 0u;
}

extern "C" void kernel_launch(void* const* d_in, const int* in_sizes, int n_in,
                              void* d_out, int out_size, void* d_ws, size_t ws_size,
                              hipStream_t stream) {
  const float* x  = (const float*)d_in[0];   // 4096x256
  const float* h  = (const float*)d_in[1];   // 4096x1024
  const float* c  = (const float*)d_in[2];   // 4096x1024
  const float* t  = (const float*)d_in[3];   // 20
  const float* Wi = (const float*)d_in[4];   // 1280x1024
  const float* bi = (const float*)d_in[5];   // 1024
  const float* Wo = (const float*)d_in[6];   // 1024x256
  const float* bo = (const float*)d_in[7];   // 256
  const float* W1 = (const float*)d_in[8];   // 1024x1024
  const float* b1 = (const float*)d_in[9];   // 1024
  const float* W2 = (const float*)d_in[10];  // 1024x1024
  const float* b2 = (const float*)d_in[11];  // 1024

  const size_t MB = 1ull << 20;
  char* ws = (char*)d_ws;
  unsigned short* W1T = (unsigned short*)(ws);                       // [0,2M)
  unsigned short* W2T = (unsigned short*)(ws + 2 * MB);              // [2,4M)
  unsigned short* WiT = (unsigned short*)(ws + 4 * MB);              // [4,6.5M)
  unsigned short* WoT = (unsigned short*)(ws + 6 * MB + 512 * 1024); // [6.5,7M)
  unsigned short* zB  = (unsigned short*)(ws + 7 * MB);              // [7,15M)

  // d_out overlays (dead before final writes) + final outputs
  float*          outF  = (float*)d_out;
  float*          hnewF = outF + 1048576;                            // [4,20M) bytes
  float*          cnewF = outF + 5242880;                            // [20,36M)
  float*          hsF   = (float*)d_out;                             // [0,16M)
  unsigned short* ksum  = (unsigned short*)((char*)d_out + 16 * MB); // [16,24M)
  unsigned short* t1    = (unsigned short*)((char*)d_out + 24 * MB); // [24,32M)
  unsigned int*   cnt   = (unsigned int*)((char*)d_out + 32 * MB);   // 256 B

  const dim3 tb(32, 8);
  transpose_f32_bf16<<<dim3(32, 32), tb, 0, stream>>>(W1, W1T, 1024, 1024);
  transpose_f32_bf16<<<dim3(32, 32), tb, 0, stream>>>(W2, W2T, 1024, 1024);
  transpose_f32_bf16<<<dim3(32, 40), tb, 0, stream>>>(Wi, WiT, 1280, 1024);
  transpose_f32_bf16<<<dim3(8, 32),  tb, 0, stream>>>(Wo, WoT, 1024, 256);

  init_h_kernel<<<16384, 256, 0, stream>>>(h, hsF, zB, cnt);

  // RK4: all 152 GEMMs in ONE persistent dispatch (panel semaphores)
  rk4_loop<<<1024, 256, 0, stream>>>(W1T, W2T, b1, b2, t,
                                     hsF, ksum, zB, t1, cnt);

  // fused gate + c_tilde -> h_new, c_new (f32 outputs)
  gemm_fused<<<dim3(8, 32), dim3(256), 0, stream>>>(x, h, zB, WiT, bi, c,
                                                    hnewF, cnewF);

  // out = h_new(f32) @ Wo + bo
  gemm_bt<4, 0><<<dim3(4, 64), dim3(256), 0, stream>>>(
      hnewF, WoT, 256, 1024, bo, nullptr, 0, 0,
      nullptr, nullptr, nullptr, nullptr, outF);
}

// Round 5
// 1736.494 us; speedup vs baseline: 7.7662x; 7.7662x over previous
//
#include <hip/hip_runtime.h>
#include <stdint.h>
#include <math.h>

// ---------------------------------------------------------------------------
// ODE-LSTM on MI355X -- RK4-algebra round (compile-fixed). f32 in/out.
// B=4096, OBS=256, H=1024, OUT=256, T=20 (19 RK4 steps).
//
// R12 = R11 + fix for the gfx950 constant-bus miscompile: uniform float
// subtraction tgrid[a]-tgrid[b] was emitted as V_ADD_F32 with TWO SGPR
// sources (illegal). vsub_uniform() routes one operand through a VGPR.
//
// Algebra (R11): u = h@W1+b1 carried across stages, W21 = W2@W1 precomputed,
// each RK4 stage is ONE GEMM:
//   u2 = u1 + 0.5dt(t1_1@W21 + c2)         c2 = b2@W1
//   u3 = u1 + 0.5dt(t1_2@W21 + c2)
//   u4 = u1 +    dt(t1_3@W21 + c2)
//   u1'= u1 + (dt/6)(T@W21) + dt*c2        T = t1_1+2t1_2+2t1_3+t1_4
//   h_ode = h + S@W2 + (t19-t0)*b2         S = sum_s (dt_s/6) T_s
// 152 GEMMs -> 78 (-48% FLOPs, -50% dispatches). All stage GEMMs: 64x64
// tiles, 4 blocks/CU, 2-phase vmcnt(4) pipeline, XCD stripe swizzle.
//
// ws (15 MiB): W21T[0,2) W2T[2,4) WiT[4,6.5) WoT[6.5,7) P0[7,15)
// d_out (36 MiB) overlays (all dead before the final writes):
//   u1b bf16 [0,8) | T bf16 [8,16) | P1 bf16 [16,24) | S bf16 [24,32)
//   W1T bf16 [32,34) (init only) | c2 f32 [34,34+4K)
// final: out f32 bytes [0,4M) | h_new [4,20M) | c_new [20,36M)
// ---------------------------------------------------------------------------

typedef __attribute__((ext_vector_type(8))) short short8;
typedef __attribute__((ext_vector_type(4))) float float4v;

#define BK 64

__device__ __forceinline__ float bf2f(unsigned short u) {
  union { unsigned int i; float f; } x;
  x.i = ((unsigned int)u) << 16;
  return x.f;
}
__device__ __forceinline__ unsigned short f2bf(float f) {
  union { float f; unsigned int i; } x;
  x.f = f;
  unsigned int r = x.i + 0x7fffu + ((x.i >> 16) & 1u);  // RNE
  return (unsigned short)(r >> 16);
}
__device__ __forceinline__ void load16(const void* g, void* l) {
  __builtin_amdgcn_global_load_lds(
      (__attribute__((address_space(1))) void*)g,
      (__attribute__((address_space(3))) void*)l, 16, 0, 0);
}
__device__ __forceinline__ short8 packbf8(const float* p) {
  float4v lo = *(const float4v*)p, hi = *(const float4v*)(p + 4);
  short8 s;
  s[0] = (short)f2bf(lo[0]); s[1] = (short)f2bf(lo[1]);
  s[2] = (short)f2bf(lo[2]); s[3] = (short)f2bf(lo[3]);
  s[4] = (short)f2bf(hi[0]); s[5] = (short)f2bf(hi[1]);
  s[6] = (short)f2bf(hi[2]); s[7] = (short)f2bf(hi[3]);
  return s;
}
// a - b for two wave-uniform floats. gfx950 has no scalar-float ALU; the
// compiler can emit V_ADD_F32 with two SGPR sources (constant-bus violation,
// R11 compile failure). Force 'a' through a VGPR first.
__device__ __forceinline__ float vsub_uniform(float a, float b) {
  float av;
  asm("v_mov_b32 %0, %1" : "=v"(av) : "s"(a));
  return av - b;
}

// ---------------------------------------------------------------------------
// C = A(MxK row-major) * Bt(NxK bf16 row-major)^T, fused per-MODE epilogue.
// 64x64 tiles, 256 threads (4 waves 2x2, 32x32 out each, acc 2x2).
// ADT: 1 = A bf16 (global_load_lds, 2-phase counted-vmcnt pipeline),
//      0 = A f32 (cvt in staging, drain loop).
// MODE: 0 INIT  u1=h@W1+b1: u1b=v, t1dst=tanh(v)
//       1 G1    u2=u1+.5dt(acc+c2): t1dst=tanh(u2), T:=reread(aux)+2*tanh
//       2 G2    u3=...: t1dst=tanh(u3), T+=2*tanh
//       3 G3    u4=u1+dt(acc+c2): T+=tanh(u4)
//       4 G4    u1'=u1+(dt/6)acc+dt*c2: u1b, t1dst=tanh, S (+)= (dt/6)*aux
//       5 ZFIN  z=h(aux)+acc+(t19-t0)*b2: t1dst=bf16(z)
//       6 WT    W21T[col*1024+row]=bf16(acc)   (builds W21^T)
//       7 OUT   outF=acc+bias
// ---------------------------------------------------------------------------
template <int MODE, int ADT>
__global__ __launch_bounds__(256, 4) void gemm_ode(
    const void* Av, const unsigned short* __restrict__ Bt,
    int N, int K,
    const float* __restrict__ bias, const float* __restrict__ tgrid,
    int step, int first,
    unsigned short* __restrict__ u1b,
    unsigned short* __restrict__ Tb,
    unsigned short* __restrict__ Sb,
    unsigned short* __restrict__ t1dst,
    const void* aux,
    const float* __restrict__ c2,
    float* __restrict__ outF) {
  __shared__ short8 AsV[2][512];  // 64 rows x 8 swizzled chunks x 16B
  __shared__ short8 BsV[2][512];

  const int t = threadIdx.x;
  int bx = blockIdx.x, by = blockIdx.y;
  // Bijective XCD stripe swizzle for (16,64): XCD x = lin&7 owns by in
  // [x*8, x*8+8). Working set/XCD: A 1MB + B 2MB = 3MB < 4MB L2.
  if (gridDim.x == 16 && gridDim.y == 64) {
    const int lin = bx + (by << 4);
    const int x = lin & 7, j = lin >> 3;  // j in 0..127
    bx = j & 15;
    by = (x << 3) | (j >> 4);
  }
  const int mBase = by * 64, nBase = bx * 64;
  const int wave = t >> 6, lane = t & 63;
  const int wr = wave >> 1, wc = wave & 1;
  const int q = lane >> 4, m16 = lane & 15;

  float4v acc[2][2];
#pragma unroll
  for (int r = 0; r < 2; ++r)
#pragma unroll
    for (int c = 0; c < 2; ++c) acc[r][c] = (float4v){0.f, 0.f, 0.f, 0.f};

  const int r0 = t >> 3;               // staging row 0..31 (also row+32)
  const int kcl = (t & 7) ^ (r0 & 7);  // swizzled k-chunk; (r0+32)&7==r0&7
  const unsigned short* aU = (const unsigned short*)Av + (size_t)(mBase + r0) * K + kcl * 8;
  const float* aF = (const float*)Av + (size_t)(mBase + r0) * K + kcl * 8;
  const unsigned short* bG = Bt + (size_t)(nBase + r0) * K + kcl * 8;

  auto computeT = [&](int buf) {
#pragma unroll
    for (int kk = 0; kk < 2; ++kk) {
      const int kc = kk * 4 + q;
      short8 af[2], bfr[2];
#pragma unroll
      for (int r = 0; r < 2; ++r) {
        const int arow = wr * 32 + r * 16 + m16;
        af[r] = AsV[buf][arow * 8 + (kc ^ (arow & 7))];
        const int brow = wc * 32 + r * 16 + m16;
        bfr[r] = BsV[buf][brow * 8 + (kc ^ (brow & 7))];
      }
#pragma unroll
      for (int r = 0; r < 2; ++r)
#pragma unroll
        for (int c = 0; c < 2; ++c)
          acc[r][c] = __builtin_amdgcn_mfma_f32_16x16x32_bf16(af[r], bfr[c],
                                                              acc[r][c], 0, 0, 0);
    }
  };

  if constexpr (ADT == 1) {
    // ---- 2-phase double-buffered pipeline, counted vmcnt(4) ----
    auto stageT = [&](int buf, int k0) {
      load16(aU + k0, &AsV[buf][t]);
      load16(aU + (size_t)32 * K + k0, &AsV[buf][t + 256]);
      load16(bG + k0, &BsV[buf][t]);
      load16(bG + (size_t)32 * K + k0, &BsV[buf][t + 256]);
    };
    stageT(0, 0);
    int cur = 0;
    for (int k0 = BK; k0 < K; k0 += BK) {
      stageT(cur ^ 1, k0);  // next tile's 4 loads join the queue
      asm volatile("s_waitcnt vmcnt(4)" ::: "memory");
      __builtin_amdgcn_sched_barrier(0);
      __builtin_amdgcn_s_barrier();
      __builtin_amdgcn_sched_barrier(0);
      computeT(cur);
      asm volatile("s_waitcnt lgkmcnt(0)" ::: "memory");
      __builtin_amdgcn_sched_barrier(0);
      __builtin_amdgcn_s_barrier();
      __builtin_amdgcn_sched_barrier(0);
      cur ^= 1;
    }
    asm volatile("s_waitcnt vmcnt(0)" ::: "memory");
    __builtin_amdgcn_sched_barrier(0);
    __builtin_amdgcn_s_barrier();
    __builtin_amdgcn_sched_barrier(0);
    computeT(cur);
  } else {
    // ---- drain loop (f32 A, cvt through VGPRs) ----
    for (int k0 = 0; k0 < K; k0 += BK) {
      AsV[0][t] = packbf8(aF + k0);
      AsV[0][t + 256] = packbf8(aF + (size_t)32 * K + k0);
      load16(bG + k0, &BsV[0][t]);
      load16(bG + (size_t)32 * K + k0, &BsV[0][t + 256]);
      __builtin_amdgcn_s_waitcnt(0);
      __syncthreads();
      computeT(0);
      __syncthreads();
    }
  }

  // ---- fused epilogue ----
  float dtv = 0.f;
  if constexpr (MODE >= 1 && MODE <= 4) dtv = vsub_uniform(tgrid[step + 1], tgrid[step]);
  if constexpr (MODE == 5) dtv = vsub_uniform(tgrid[step], tgrid[0]);

  const int colBase = nBase + wc * 32 + m16;
  const int rowBase = mBase + wr * 32 + q * 4;
#pragma unroll
  for (int r = 0; r < 2; ++r) {
#pragma unroll
    for (int c = 0; c < 2; ++c) {
      const int col = colBase + c * 16;
#pragma unroll
      for (int e = 0; e < 4; ++e) {
        const int row = rowBase + r * 16 + e;
        const size_t idx = (size_t)row * N + col;
        const float v = acc[r][c][e];
        if constexpr (MODE == 0) {
          const float u1 = v + bias[col];
          u1b[idx] = f2bf(u1);
          t1dst[idx] = f2bf(tanhf(u1));
        } else if constexpr (MODE == 1) {
          const float u2 = bf2f(u1b[idx]) + 0.5f * dtv * (v + c2[col]);
          const float th = tanhf(u2);
          t1dst[idx] = f2bf(th);
          Tb[idx] = f2bf(bf2f(((const unsigned short*)aux)[idx]) + 2.f * th);
        } else if constexpr (MODE == 2) {
          const float u3 = bf2f(u1b[idx]) + 0.5f * dtv * (v + c2[col]);
          const float th = tanhf(u3);
          t1dst[idx] = f2bf(th);
          Tb[idx] = f2bf(bf2f(Tb[idx]) + 2.f * th);
        } else if constexpr (MODE == 3) {
          const float u4 = bf2f(u1b[idx]) + dtv * (v + c2[col]);
          Tb[idx] = f2bf(bf2f(Tb[idx]) + tanhf(u4));
        } else if constexpr (MODE == 4) {
          const float u1n = bf2f(u1b[idx]) + (dtv * (1.f / 6.f)) * v + dtv * c2[col];
          u1b[idx] = f2bf(u1n);
          t1dst[idx] = f2bf(tanhf(u1n));
          const float sOld = first ? 0.f : bf2f(Sb[idx]);
          Sb[idx] = f2bf(sOld + (dtv * (1.f / 6.f)) *
                                    bf2f(((const unsigned short*)aux)[idx]));
        } else if constexpr (MODE == 5) {
          const float z = ((const float*)aux)[idx] + v + dtv * bias[col];
          t1dst[idx] = f2bf(z);
        } else if constexpr (MODE == 6) {
          t1dst[(size_t)col * 1024 + row] = f2bf(v);
        } else {  // MODE 7: out projection
          outF[idx] = v + bias[col];
        }
      }
    }
  }
}

// Fused gate + c_tilde dual GEMM, 64x64 tiles (4 blocks/CU):
// accG = [x|h]@WiT^T, accC = [x|z]@WiT^T; epilogue -> h_new, c_new.
__global__ __launch_bounds__(256, 4) void gemm_fused(
    const float* __restrict__ x, const float* __restrict__ h,
    const unsigned short* __restrict__ zB,
    const unsigned short* __restrict__ WiT,  // 1024 x 1280 bf16
    const float* __restrict__ bi, const float* __restrict__ c_in,
    float* __restrict__ hnewF, float* __restrict__ cnewF) {
  __shared__ short8 AsG[512];
  __shared__ short8 AsC[512];
  __shared__ short8 Bs[512];

  const int t = threadIdx.x;
  int bx = blockIdx.x, by = blockIdx.y;
  if (gridDim.x == 16 && gridDim.y == 64) {
    const int lin = bx + (by << 4);
    const int xc = lin & 7, j = lin >> 3;
    bx = j & 15;
    by = (xc << 3) | (j >> 4);
  }
  const int mBase = by * 64, nBase = bx * 64;
  const int wave = t >> 6, lane = t & 63;
  const int wr = wave >> 1, wc = wave & 1;
  const int q = lane >> 4, m16 = lane & 15;

  float4v accG[2][2], accC[2][2];
#pragma unroll
  for (int r = 0; r < 2; ++r)
#pragma unroll
    for (int c = 0; c < 2; ++c) {
      accG[r][c] = (float4v){0.f, 0.f, 0.f, 0.f};
      accC[r][c] = (float4v){0.f, 0.f, 0.f, 0.f};
    }

  const int r0 = t >> 3;
  const int kcl = (t & 7) ^ (r0 & 7);

  for (int k0 = 0; k0 < 1280; k0 += BK) {
    const bool isX = (k0 < 256);
#pragma unroll
    for (int i = 0; i < 2; ++i) {
      const int row = mBase + r0 + i * 32;
      short8 sg, sc;
      if (isX) {
        sg = packbf8(x + (size_t)row * 256 + k0 + kcl * 8);
        sc = sg;
      } else {
        const size_t off = (size_t)row * 1024 + (k0 - 256) + kcl * 8;
        sg = packbf8(h + off);
        sc = *(const short8*)(zB + off);
      }
      AsG[i * 256 + t] = sg;
      AsC[i * 256 + t] = sc;
      load16(WiT + (size_t)(nBase + r0 + i * 32) * 1280 + k0 + kcl * 8,
             &Bs[i * 256 + t]);
    }
    __builtin_amdgcn_s_waitcnt(0);
    __syncthreads();

#pragma unroll
    for (int kk = 0; kk < 2; ++kk) {
      const int kc = kk * 4 + q;
      short8 ag[2], ac[2], bfr[2];
#pragma unroll
      for (int r = 0; r < 2; ++r) {
        const int arow = wr * 32 + r * 16 + m16;
        ag[r] = AsG[arow * 8 + (kc ^ (arow & 7))];
        ac[r] = AsC[arow * 8 + (kc ^ (arow & 7))];
        const int brow = wc * 32 + r * 16 + m16;
        bfr[r] = Bs[brow * 8 + (kc ^ (brow & 7))];
      }
#pragma unroll
      for (int r = 0; r < 2; ++r)
#pragma unroll
        for (int c = 0; c < 2; ++c) {
          accG[r][c] = __builtin_amdgcn_mfma_f32_16x16x32_bf16(ag[r], bfr[c],
                                                               accG[r][c], 0, 0, 0);
          accC[r][c] = __builtin_amdgcn_mfma_f32_16x16x32_bf16(ac[r], bfr[c],
                                                               accC[r][c], 0, 0, 0);
        }
    }
    __syncthreads();
  }

  const int colBase = nBase + wc * 32 + m16;
  const int rowBase = mBase + wr * 32 + q * 4;
#pragma unroll
  for (int r = 0; r < 2; ++r) {
#pragma unroll
    for (int c = 0; c < 2; ++c) {
      const int col = colBase + c * 16;
      const float bv = bi[col];
#pragma unroll
      for (int e = 0; e < 4; ++e) {
        const int row = rowBase + r * 16 + e;
        const size_t idx = (size_t)row * 1024 + col;
        const float g = 1.f / (1.f + expf(-(accG[r][c][e] + bv)));
        const float ct = 1.f / (1.f + expf(-(accC[r][c][e] + bv)));
        const float cn = g * (c_in[idx] + ct);
        const float hn = g * tanhf(cn);
        hnewF[idx] = hn;
        cnewF[idx] = cn;
      }
    }
  }
}

// out[c][r] = bf16(in[r][c]); in f32 RxC. block (32,8), grid (C/32, R/32).
__global__ __launch_bounds__(256) void transpose_f32_bf16(
    const float* __restrict__ in, unsigned short* __restrict__ out,
    int R, int C) {
  __shared__ float tile[32][33];
  const int c0 = blockIdx.x * 32, r0 = blockIdx.y * 32;
  const int tx = threadIdx.x, ty = threadIdx.y;
#pragma unroll
  for (int i = 0; i < 32; i += 8)
    tile[ty + i][tx] = in[(size_t)(r0 + ty + i) * C + c0 + tx];
  __syncthreads();
#pragma unroll
  for (int i = 0; i < 32; i += 8)
    out[(size_t)(c0 + ty + i) * R + r0 + tx] = f2bf(tile[tx][ty + i]);
}

// c2[n] = sum_k b2[k] * W1[k,n]  (1024-dot per thread; one-off, tiny)
__global__ __launch_bounds__(256) void c2_gemv(
    const float* __restrict__ b2, const float* __restrict__ W1,
    float* __restrict__ c2v) {
  const int n = blockIdx.x * 256 + threadIdx.x;
  float a = 0.f;
  for (int k = 0; k < 1024; ++k) a += b2[k] * W1[(size_t)k * 1024 + n];
  c2v[n] = a;
}

extern "C" void kernel_launch(void* const* d_in, const int* in_sizes, int n_in,
                              void* d_out, int out_size, void* d_ws, size_t ws_size,
                              hipStream_t stream) {
  const float* x  = (const float*)d_in[0];   // 4096x256
  const float* h  = (const float*)d_in[1];   // 4096x1024
  const float* c  = (const float*)d_in[2];   // 4096x1024
  const float* t  = (const float*)d_in[3];   // 20
  const float* Wi = (const float*)d_in[4];   // 1280x1024
  const float* bi = (const float*)d_in[5];   // 1024
  const float* Wo = (const float*)d_in[6];   // 1024x256
  const float* bo = (const float*)d_in[7];   // 256
  const float* W1 = (const float*)d_in[8];   // 1024x1024
  const float* b1 = (const float*)d_in[9];   // 1024
  const float* W2 = (const float*)d_in[10];  // 1024x1024
  const float* b2 = (const float*)d_in[11];  // 1024

  const size_t MB = 1ull << 20;
  char* ws = (char*)d_ws;
  unsigned short* W21T = (unsigned short*)(ws);                      // [0,2M)
  unsigned short* W2T  = (unsigned short*)(ws + 2 * MB);             // [2,4M)
  unsigned short* WiT  = (unsigned short*)(ws + 4 * MB);             // [4,6.5M)
  unsigned short* WoT  = (unsigned short*)(ws + 6 * MB + 512 * 1024);// [6.5,7M)
  unsigned short* P0   = (unsigned short*)(ws + 7 * MB);             // [7,15M)

  // d_out overlays (all dead before the final output writes)
  float*          outF  = (float*)d_out;
  float*          hnewF = outF + 1048576;                            // [4,20M)
  float*          cnewF = outF + 5242880;                            // [20,36M)
  unsigned short* u1b   = (unsigned short*)d_out;                    // [0,8M)
  unsigned short* Tb    = (unsigned short*)((char*)d_out + 8 * MB);  // [8,16M)
  unsigned short* P1    = (unsigned short*)((char*)d_out + 16 * MB); // [16,24M)
  unsigned short* Sb    = (unsigned short*)((char*)d_out + 24 * MB); // [24,32M)
  unsigned short* W1T   = (unsigned short*)((char*)d_out + 32 * MB); // [32,34M)
  float*          c2v   = (float*)((char*)d_out + 34 * MB);          // 4 KB

  const dim3 tb(32, 8), blk(256), g(16, 64);

  // weight prep
  transpose_f32_bf16<<<dim3(32, 32), tb, 0, stream>>>(W1, W1T, 1024, 1024);
  transpose_f32_bf16<<<dim3(32, 32), tb, 0, stream>>>(W2, W2T, 1024, 1024);
  transpose_f32_bf16<<<dim3(32, 40), tb, 0, stream>>>(Wi, WiT, 1280, 1024);
  transpose_f32_bf16<<<dim3(8, 32),  tb, 0, stream>>>(Wo, WoT, 1024, 256);
  c2_gemv<<<4, blk, 0, stream>>>(b2, W1, c2v);
  // W21T = (W2@W1)^T
  gemm_ode<6, 0><<<dim3(16, 16), blk, 0, stream>>>(
      W2, W1T, 1024, 1024, b1, t, 0, 0,
      nullptr, nullptr, nullptr, W21T, nullptr, nullptr, nullptr);
  // u1 = h@W1 + b1 ; t1_1 = tanh(u1) -> P0
  gemm_ode<0, 0><<<g, blk, 0, stream>>>(
      h, W1T, 1024, 1024, b1, t, 0, 0,
      u1b, nullptr, nullptr, P0, nullptr, nullptr, nullptr);

  // RK4: 19 steps x 4 single GEMMs (all vs W21T)
  for (int s = 0; s < 19; ++s) {
    gemm_ode<1, 1><<<g, blk, 0, stream>>>(
        P0, W21T, 1024, 1024, b1, t, s, 0,
        u1b, Tb, nullptr, P1, P0, c2v, nullptr);
    gemm_ode<2, 1><<<g, blk, 0, stream>>>(
        P1, W21T, 1024, 1024, b1, t, s, 0,
        u1b, Tb, nullptr, P0, nullptr, c2v, nullptr);
    gemm_ode<3, 1><<<g, blk, 0, stream>>>(
        P0, W21T, 1024, 1024, b1, t, s, 0,
        u1b, Tb, nullptr, nullptr, nullptr, c2v, nullptr);
    gemm_ode<4, 1><<<g, blk, 0, stream>>>(
        Tb, W21T, 1024, 1024, b1, t, s, (s == 0) ? 1 : 0,
        u1b, nullptr, Sb, P0, Tb, c2v, nullptr);
  }

  // z = h_ode = h + S@W2 + (t19-t0)*b2  -> bf16 into P0
  gemm_ode<5, 1><<<g, blk, 0, stream>>>(
      Sb, W2T, 1024, 1024, b2, t, 19, 0,
      nullptr, nullptr, nullptr, P0, h, nullptr, nullptr);

  // fused gate + c_tilde -> h_new, c_new (f32)
  gemm_fused<<<g, blk, 0, stream>>>(x, h, P0, WiT, bi, c, hnewF, cnewF);

  // out = h_new(f32) @ Wo + bo
  gemm_ode<7, 0><<<dim3(4, 64), blk, 0, stream>>>(
      hnewF, WoT, 256, 1024, bo, t, 0, 0,
      nullptr, nullptr, nullptr, nullptr, nullptr, nullptr, outF);
}